// Round 11
// baseline (386.495 us; speedup 1.0000x reference)
//
#include <hip/hip_runtime.h>
#include <hip/hip_bf16.h>
#include <stdint.h>

typedef __hip_bfloat16 bf16;
typedef short s16x8 __attribute__((ext_vector_type(8)));
typedef float f32x4 __attribute__((ext_vector_type(4)));

#define B_ 4
#define C_ 1024
#define D_ 1024
#define H_ 16
#define K_ 716   // int(1024 * 0.7)

static __device__ __forceinline__ short f2b(float f) {
    __hip_bfloat16 h = __float2bfloat16(f);
    short s; __builtin_memcpy(&s, &h, 2); return s;
}
static __device__ __forceinline__ f32x4 mfma16(s16x8 a, s16x8 b, f32x4 c) {
    return __builtin_amdgcn_mfma_f32_16x16x32_bf16(a, b, c, 0, 0, 0);
}
static __device__ __forceinline__ void gl_lds16(const void* g, void* l) {
    __builtin_amdgcn_global_load_lds((const __attribute__((address_space(1))) void*)g,
                                     (__attribute__((address_space(3))) void*)l, 16, 0, 0);
}

// ---------------------------------------------------------------------------
// Prepass: convert activations + weights fp32 -> bf16 (vectorized, 8/thread)
// ---------------------------------------------------------------------------
__global__ __launch_bounds__(256) void cvt_pass(
        const float* __restrict__ q, const float* __restrict__ k, const float* __restrict__ v,
        const float* __restrict__ wq, const float* __restrict__ wk,
        const float* __restrict__ wv, const float* __restrict__ wo,
        bf16* __restrict__ xq, bf16* __restrict__ xk, bf16* __restrict__ xv,
        bf16* __restrict__ owq, bf16* __restrict__ owk, bf16* __restrict__ owv,
        bf16* __restrict__ owo)
{
    const int nchunk = 16777216 / 8;   // 2M chunks of 8 f32
    for (int cid = blockIdx.x * 256 + threadIdx.x; cid < nchunk; cid += gridDim.x * 256) {
        const int e = cid * 8;
        const float* src; bf16* dst; int off;
        if      (e < 4194304)  { src = q;  dst = xq;  off = e; }
        else if (e < 8388608)  { src = k;  dst = xk;  off = e - 4194304; }
        else if (e < 12582912) { src = v;  dst = xv;  off = e - 8388608; }
        else if (e < 13631488) { src = wq; dst = owq; off = e - 12582912; }
        else if (e < 14680064) { src = wk; dst = owk; off = e - 13631488; }
        else if (e < 15728640) { src = wv; dst = owv; off = e - 14680064; }
        else                   { src = wo; dst = owo; off = e - 15728640; }
        float4 f0 = ((const float4*)(src + off))[0];
        float4 f1 = ((const float4*)(src + off))[1];
        s16x8 o;
        o[0]=f2b(f0.x); o[1]=f2b(f0.y); o[2]=f2b(f0.z); o[3]=f2b(f0.w);
        o[4]=f2b(f1.x); o[5]=f2b(f1.y); o[6]=f2b(f1.z); o[7]=f2b(f1.w);
        *(s16x8*)(dst + off) = o;
    }
}

// stage a ROWSx64 bf16 tile via global_load_lds(16B), pre-swizzled source
// (rule #21: linear LDS dest + inverse-swizzled global src + swizzled read)
template<int ROWS>
static __device__ __forceinline__ void stage_tile(const bf16* gtile, bf16* lds, int tid) {
    #pragma unroll
    for (int u = 0; u < ROWS / 32; ++u) {
        const int lin  = u * 4096 + tid * 16;                 // byte in tile
        const int row  = lin >> 7;
        const int colb = (lin & 127) ^ ((row & 7) << 4);
        gl_lds16((const char*)(gtile + (size_t)row * 1024) + colb,
                 (char*)lds + (lin & ~1023));
    }
}
#define LDS_FRAG(buf, row, kk) \
    (*(const s16x8*)((const char*)(buf) + (row) * 128 + (((kk) * 64 + g * 16) ^ (((row) & 7) << 4))))

// ---------------------------------------------------------------------------
// Grouped QKV projection GEMM (all-bf16): out = A @ W^T + bias. 128x128, BK=64.
// ---------------------------------------------------------------------------
__global__ __launch_bounds__(256, 4) void proj_gemm(
        const bf16* __restrict__ xq, const bf16* __restrict__ xk, const bf16* __restrict__ xv,
        const bf16* __restrict__ wqb, const bf16* __restrict__ wkb, const bf16* __restrict__ wvb,
        const float* __restrict__ bq, const float* __restrict__ bk, const float* __restrict__ bv,
        bf16* __restrict__ qb, bf16* __restrict__ kb, bf16* __restrict__ vT)
{
    __shared__ bf16 As[128 * 64];
    __shared__ bf16 Bs[128 * 64];
    const int z = blockIdx.z;
    const bf16* Ap = (z == 0) ? xq : ((z == 1) ? xk : xv);
    const bf16* Wp = (z == 0) ? wqb : ((z == 1) ? wkb : wvb);
    const float* bp = (z == 0) ? bq : ((z == 1) ? bk : bv);
    const int tid = threadIdx.x;
    const int l = tid & 63, w = tid >> 6, g = l >> 4, c = l & 15;
    const int wm = w & 1, wn = w >> 1;
    const int n0 = blockIdx.x * 128, m0 = blockIdx.y * 128;

    f32x4 acc[4][4] = {};

    for (int kt = 0; kt < 16; ++kt) {
        stage_tile<128>(Ap + (size_t)m0 * 1024 + kt * 64, As, tid);
        stage_tile<128>(Wp + (size_t)n0 * 1024 + kt * 64, Bs, tid);
        __syncthreads();
        #pragma unroll
        for (int kk = 0; kk < 2; ++kk) {
            s16x8 af[4], bfv[4];
            #pragma unroll
            for (int i = 0; i < 4; ++i) af[i]  = LDS_FRAG(As, wm * 64 + i * 16 + c, kk);
            #pragma unroll
            for (int j = 0; j < 4; ++j) bfv[j] = LDS_FRAG(Bs, wn * 64 + j * 16 + c, kk);
            #pragma unroll
            for (int i = 0; i < 4; ++i)
                #pragma unroll
                for (int j = 0; j < 4; ++j)
                    acc[i][j] = mfma16(af[i], bfv[j], acc[i][j]);
        }
        __syncthreads();
    }
    const float scale = (z == 0) ? 0.125f : 1.0f;
    #pragma unroll
    for (int j = 0; j < 4; ++j) {
        const int coln = n0 + wn * 64 + j * 16 + c;
        const float bias = bp[coln];
        #pragma unroll
        for (int i = 0; i < 4; ++i) {
            #pragma unroll
            for (int jj = 0; jj < 4; ++jj) {
                const int rowm = m0 + wm * 64 + i * 16 + g * 4 + jj;
                const float val = (acc[i][j][jj] + bias) * scale;
                if (z == 0) {
                    qb[(size_t)rowm * 1024 + coln] = __float2bfloat16(val);
                } else if (z == 1) {
                    kb[(size_t)rowm * 1024 + coln] = __float2bfloat16(val);
                } else {
                    const int b = rowm >> 10, n = rowm & 1023;
                    const int h = coln >> 6, dh = coln & 63;
                    vT[((size_t)((b * H_ + h) * 64 + dh) << 10) + n] = __float2bfloat16(val);
                }
            }
        }
    }
}

// ---------------------------------------------------------------------------
// Output GEMM: out(f32) = ctxb(bf16) @ Wo^T + bo.  BM=128, BN=64, BK=64.
// ---------------------------------------------------------------------------
__global__ __launch_bounds__(256, 4) void out_gemm(
        const bf16* __restrict__ Ab, const bf16* __restrict__ Wb,
        const float* __restrict__ bias, float* __restrict__ out)
{
    __shared__ bf16 As[128 * 64];
    __shared__ bf16 Bs[64 * 64];
    const int tid = threadIdx.x;
    const int l = tid & 63, w = tid >> 6, g = l >> 4, c = l & 15;
    const int wm = w & 1, wn = w >> 1;
    const int n0 = blockIdx.x * 64, m0 = blockIdx.y * 128;

    f32x4 acc[4][2] = {};

    for (int kt = 0; kt < 16; ++kt) {
        stage_tile<128>(Ab + (size_t)m0 * 1024 + kt * 64, As, tid);
        stage_tile<64>(Wb + (size_t)n0 * 1024 + kt * 64, Bs, tid);
        __syncthreads();
        #pragma unroll
        for (int kk = 0; kk < 2; ++kk) {
            s16x8 af[4], bfv[2];
            #pragma unroll
            for (int i = 0; i < 4; ++i) af[i]  = LDS_FRAG(As, wm * 64 + i * 16 + c, kk);
            #pragma unroll
            for (int j = 0; j < 2; ++j) bfv[j] = LDS_FRAG(Bs, wn * 32 + j * 16 + c, kk);
            #pragma unroll
            for (int i = 0; i < 4; ++i)
                #pragma unroll
                for (int j = 0; j < 2; ++j)
                    acc[i][j] = mfma16(af[i], bfv[j], acc[i][j]);
        }
        __syncthreads();
    }
    #pragma unroll
    for (int j = 0; j < 2; ++j) {
        const int coln = n0 + wn * 32 + j * 16 + c;
        const float bv = bias[coln];
        #pragma unroll
        for (int i = 0; i < 4; ++i)
            #pragma unroll
            for (int jj = 0; jj < 4; ++jj) {
                const int rowm = m0 + wm * 64 + i * 16 + g * 4 + jj;
                out[(size_t)rowm * 1024 + coln] = acc[i][j][jj] + bv;
            }
    }
}

// ---------------------------------------------------------------------------
// Fused attention, 16 q-rows/block, 256 threads, 32 KiB LDS (5 blocks/CU).
// ---------------------------------------------------------------------------
__global__ __launch_bounds__(256, 5) void attn_topk(
        const bf16* __restrict__ qb, const bf16* __restrict__ kb,
        const bf16* __restrict__ vT, bf16* __restrict__ ctx)
{
    __shared__ bf16 S[16 * 1024];      // 32 KiB; rows swizzled by (row&15)<<4
    const int bid = blockIdx.x;
    const int wid = (bid & 7) * 512 + (bid >> 3);   // XCD-chunked (4096 = 8*512)
    const int qt = wid & 63, h = (wid >> 6) & 15, b = wid >> 10;
    const int qr0 = qt * 16;
    const int tid = threadIdx.x, w = tid >> 6, l = tid & 63, g = l >> 4, c = l & 15;

    const size_t batchoff = (size_t)b * C_ * D_;
    const bf16* qrow  = qb + batchoff + (size_t)qr0 * 1024 + h * 64;
    const bf16* kbase = kb + batchoff + h * 64;

    // q fragments (16 rows, shared by all 4 waves)
    s16x8 aq[2];
    #pragma unroll
    for (int kk = 0; kk < 2; ++kk)
        aq[kk] = *(const s16x8*)(qrow + (size_t)c * 1024 + kk * 32 + g * 8);

    // ---- phase 1: S = q k^T, wave w covers cols [w*256, w*256+256) --------
    auto ldk = [&](int nf, int kk) {
        const int ncol = w * 256 + nf * 16;
        return *(const s16x8*)(kbase + (size_t)(ncol + c) * 1024 + kk * 32 + g * 8);
    };
    s16x8 b0 = ldk(0, 0), b1 = ldk(0, 1);
    #pragma unroll 1
    for (int nf = 0; nf < 16; ++nf) {
        s16x8 nb0 = b0, nb1 = b1;
        if (nf < 15) { nb0 = ldk(nf + 1, 0); nb1 = ldk(nf + 1, 1); }
        const int ncol = w * 256 + nf * 16;
        f32x4 accS = {0.f, 0.f, 0.f, 0.f};
        accS = mfma16(aq[0], b0, accS);
        accS = mfma16(aq[1], b1, accS);
        #pragma unroll
        for (int jj = 0; jj < 4; ++jj) {
            const int row = g * 4 + jj;
            *(bf16*)((char*)S + row * 2048 + (((ncol + c) * 2) ^ (row << 4))) =
                __float2bfloat16(accS[jj]);
        }
        b0 = nb0; b1 = nb1;
    }
    __syncthreads();

    // ---- phase 2: exact top-K + softmax; wave w owns rows w*4..w*4+3 ------
    int um[4][16]; int mx[4];
    #pragma unroll
    for (int i = 0; i < 4; ++i) {
        const int r = w * 4 + i;
        const int swz = r << 4;
        uint4 xa = *(const uint4*)((const char*)S + r * 2048 + ((l * 16) ^ swz));
        uint4 xb = *(const uint4*)((const char*)S + r * 2048 + ((1024 + l * 16) ^ swz));
        unsigned xs[8] = {xa.x, xa.y, xa.z, xa.w, xb.x, xb.y, xb.z, xb.w};
        int m = 0;
        #pragma unroll
        for (int q = 0; q < 8; ++q) {
            unsigned x = xs[q];
            unsigned mmk = 0x80008000u | (((x >> 15) & 0x00010001u) * 0x7FFFu);
            unsigned y = x ^ mmk;
            um[i][2 * q]     = (int)(y & 0xFFFFu);
            um[i][2 * q + 1] = (int)(y >> 16);
            m = max(m, max(um[i][2 * q], um[i][2 * q + 1]));
        }
        #pragma unroll
        for (int off = 32; off; off >>= 1) m = max(m, __shfl_xor(m, off));
        mx[i] = m;
    }
    int p0 = 0, p1 = 0, p2 = 0, p3 = 0;
    #pragma unroll 1
    for (int bit = 15; bit >= 0; --bit) {
        const int t0 = p0 | (1 << bit), t1 = p1 | (1 << bit);
        const int t2 = p2 | (1 << bit), t3 = p3 | (1 << bit);
        int c0 = 0, c1 = 0, c2 = 0, c3 = 0;
        #pragma unroll
        for (int j = 0; j < 16; ++j) {
            c0 += __popcll(__ballot(um[0][j] >= t0));
            c1 += __popcll(__ballot(um[1][j] >= t1));
            c2 += __popcll(__ballot(um[2][j] >= t2));
            c3 += __popcll(__ballot(um[3][j] >= t3));
        }
        if (c0 >= K_) p0 = t0;
        if (c1 >= K_) p1 = t1;
        if (c2 >= K_) p2 = t2;
        if (c3 >= K_) p3 = t3;
    }
    const int pp[4] = {p0, p1, p2, p3};
    #pragma unroll
    for (int i = 0; i < 4; ++i) {
        const int r = w * 4 + i;
        const int MX = mx[i], PP = pp[i];
        const int rawm = (MX & 0x8000) ? (MX ^ 0x8000) : ((~MX) & 0xFFFF);
        const float smax = __uint_as_float(((unsigned)rawm) << 16);
        float e[16]; float ls = 0.f;
        #pragma unroll
        for (int j = 0; j < 16; ++j) {
            const int v = um[i][j];
            const int rb = (v & 0x8000) ? (v ^ 0x8000) : ((~v) & 0xFFFF);
            const float s = __uint_as_float(((unsigned)rb) << 16);
            const float ee = __expf(s - smax);
            e[j] = (v >= PP) ? ee : 0.f;
            ls += e[j];
        }
        #pragma unroll
        for (int off = 32; off; off >>= 1) ls += __shfl_xor(ls, off);
        const float inv = 1.0f / ls;
        unsigned o[8];
        #pragma unroll
        for (int jp = 0; jp < 8; ++jp) {
            const unsigned lo = (unsigned short)f2b(e[2 * jp] * inv);
            const unsigned hi = (unsigned short)f2b(e[2 * jp + 1] * inv);
            o[jp] = lo | (hi << 16);
        }
        const int swz = r << 4;
        *(uint4*)((char*)S + r * 2048 + ((l * 16) ^ swz)) = make_uint4(o[0], o[1], o[2], o[3]);
        *(uint4*)((char*)S + r * 2048 + ((1024 + l * 16) ^ swz)) = make_uint4(o[4], o[5], o[6], o[7]);
    }
    __syncthreads();

    // ---- phase 3: ctx = P @ v; wave w -> cols [w*16, w*16+16), rows 0..15 -
    {
        const int nt = w;
        const bf16* vb = vT + ((size_t)((b * H_ + h) * 64 + nt * 16 + c) << 10) + g * 8;
        const int srow = c;
        const int ssz = srow << 4;
        s16x8 v0 = *(const s16x8*)(vb + 0 * 32);
        s16x8 v1 = *(const s16x8*)(vb + 1 * 32);
        s16x8 v2 = *(const s16x8*)(vb + 2 * 32);
        s16x8 v3 = *(const s16x8*)(vb + 3 * 32);
        f32x4 acc = {0.f, 0.f, 0.f, 0.f};
        #pragma unroll 1
        for (int kt4 = 0; kt4 < 8; ++kt4) {
            s16x8 n0 = v0, n1 = v1, n2 = v2, n3 = v3;
            if (kt4 < 7) {
                n0 = *(const s16x8*)(vb + (kt4 * 4 + 4) * 32);
                n1 = *(const s16x8*)(vb + (kt4 * 4 + 5) * 32);
                n2 = *(const s16x8*)(vb + (kt4 * 4 + 6) * 32);
                n3 = *(const s16x8*)(vb + (kt4 * 4 + 7) * 32);
            }
            #pragma unroll
            for (int u = 0; u < 4; ++u) {
                const s16x8 af = *(const s16x8*)((const char*)S + srow * 2048 +
                                    ((((kt4 * 4 + u) * 64) + g * 16) ^ ssz));
                const s16x8 bv = (u == 0) ? v0 : (u == 1) ? v1 : (u == 2) ? v2 : v3;
                acc = mfma16(af, bv, acc);
            }
            v0 = n0; v1 = n1; v2 = n2; v3 = n3;
        }
        #pragma unroll
        for (int jj = 0; jj < 4; ++jj) {
            const int row = g * 4 + jj;
            ctx[batchoff + (size_t)(qr0 + row) * 1024 + h * 64 + nt * 16 + c] =
                __float2bfloat16(acc[jj]);
        }
    }
}

extern "C" void kernel_launch(void* const* d_in, const int* in_sizes, int n_in,
                              void* d_out, int out_size, void* d_ws, size_t ws_size,
                              hipStream_t stream)
{
    const float* key   = (const float*)d_in[0];
    const float* value = (const float*)d_in[1];
    const float* query = (const float*)d_in[2];
    const float* Wq = (const float*)d_in[3];
    const float* bq = (const float*)d_in[4];
    const float* Wk = (const float*)d_in[5];
    const float* bk = (const float*)d_in[6];
    const float* Wv = (const float*)d_in[7];
    const float* bv = (const float*)d_in[8];
    const float* Wo = (const float*)d_in[9];
    const float* bo = (const float*)d_in[10];

    char* ws = (char*)d_ws;
    bf16* qb   = (bf16*)(ws);                   // 8 MiB (pre-scaled by 1/8)
    bf16* kb   = (bf16*)(ws + (8u  << 20));     // 8 MiB
    bf16* vT   = (bf16*)(ws + (16u << 20));     // 8 MiB, [B*H][64][1024]
    bf16* xq   = (bf16*)(ws + (24u << 20));     // 8 MiB query bf16
    bf16* xk   = (bf16*)(ws + (32u << 20));     // 8 MiB key bf16
    bf16* xv   = (bf16*)(ws + (40u << 20));     // 8 MiB value bf16
    bf16* wqb  = (bf16*)(ws + (48u << 20));     // 2 MiB
    bf16* wkb  = (bf16*)(ws + (50u << 20));     // 2 MiB
    bf16* wvb  = (bf16*)(ws + (52u << 20));     // 2 MiB
    bf16* wob  = (bf16*)(ws + (54u << 20));     // 2 MiB
    bf16* ctxb = xq;   // alias: xq dead after proj_gemm; stream order serializes

    hipLaunchKernelGGL(cvt_pass, dim3(2048), dim3(256), 0, stream,
                       query, key, value, Wq, Wk, Wv, Wo,
                       xq, xk, xv, wqb, wkb, wvb, wob);
    hipLaunchKernelGGL(proj_gemm, dim3(8, 32, 3), dim3(256), 0, stream,
                       xq, xk, xv, wqb, wkb, wvb, bq, bk, bv, qb, kb, vT);
    hipLaunchKernelGGL(attn_topk, dim3(4096), dim3(256), 0, stream, qb, kb, vT, ctxb);
    hipLaunchKernelGGL(out_gemm, dim3(16, 32), dim3(256), 0, stream, ctxb, wob, bo, (float*)d_out);
}